// Round 18
// baseline (1264.242 us; speedup 1.0000x reference)
//
#include <hip/hip_runtime.h>
#include <math.h>

#define EMB   256
#define TWOE  512
#define NINIT 1024
#define NSTEP 512
#define NPS   256
#define TOTAL (NINIT + NSTEP * NPS)   // 132096
#define MM    65536
#define NNODE (NSTEP * NPS)           // 131072
#define NKEY  2048                    // 256 levels x 8 rules
#define BTH   512
#define TROWS 32                      // rows per tile
#define CHK_SH  16384                 // shorts per chunk (hi 8192 + lo 8192) = 32KB
#define RULE_SH (24 * CHK_SH)         // 24 chunks per rule (16 W1 + 8 W2)

typedef short s16x8 __attribute__((ext_vector_type(8)));
typedef float f32x4 __attribute__((ext_vector_type(4)));

// ---- workspace layout (bytes) ----
#define OFF_VECH   0ull
#define OFF_VECL   ((size_t)TOTAL * EMB * 2)            // 67633152
#define OFF_VAL    (2ull * (size_t)TOTAL * EMB * 2)     // 135266304
#define OFF_CNT    (OFF_VAL + (size_t)MM * 4)           // done[256]
#define OFF_ACC    (OFF_CNT + 4096)
#define OFF_KCNT   (OFF_ACC + 256)
#define OFF_KOFS   (OFF_KCNT + (size_t)NKEY * 4)
#define OFF_NL     (OFF_KOFS + (size_t)NKEY * 4)
#define OFF_TPL    (OFF_NL + 256)
#define OFF_BROWS  (OFF_TPL + 4096)
#define OFF_WSPLIT (OFF_BROWS + (size_t)NNODE * 4)      // +6291456

// acc layout: [0]=sum(pos) [1]=sum(neg) [2]=loss [3]=posOK [4]=negOK

// ---- coherence-point (bypass L1/L2) ops ----
__device__ __forceinline__ void store_dev_u32(unsigned* p, unsigned v) {
  asm volatile("global_store_dword %0, %1, off sc0 sc1" :: "v"(p), "v"(v) : "memory");
}
__device__ __forceinline__ void store_dev_b64(void* p, uint2 v) {
  asm volatile("global_store_dwordx2 %0, %1, off sc0 sc1" :: "v"(p), "v"(v) : "memory");
}
__device__ __forceinline__ void store_dev_b128(void* p, uint4 v) {
  store_dev_b64(p, make_uint2(v.x, v.y));
  store_dev_b64((char*)p + 8, make_uint2(v.z, v.w));
}
__device__ __forceinline__ unsigned load_dev_u32(const unsigned* p) {
  unsigned r;
  asm volatile("global_load_dword %0, %1, off sc0 sc1\n\ts_waitcnt vmcnt(0)"
               : "=v"(r) : "v"(p) : "memory");
  return r;
}

// counted wait: vmcnt(N) + lgkmcnt(0) (N compile-time after unroll)
__device__ __forceinline__ void wait_vm_lgkm(int n) {
  switch (n) {
    case 0:  asm volatile("s_waitcnt vmcnt(0) lgkmcnt(0)"  ::: "memory"); break;
    case 4:  asm volatile("s_waitcnt vmcnt(4) lgkmcnt(0)"  ::: "memory"); break;
    case 6:  asm volatile("s_waitcnt vmcnt(6) lgkmcnt(0)"  ::: "memory"); break;
    case 8:  asm volatile("s_waitcnt vmcnt(8) lgkmcnt(0)"  ::: "memory"); break;
    case 10: asm volatile("s_waitcnt vmcnt(10) lgkmcnt(0)" ::: "memory"); break;
    default: asm volatile("s_waitcnt vmcnt(12) lgkmcnt(0)" ::: "memory"); break;
  }
}

// split helpers (truncation split f32 -> bf16 hi + bf16 lo)
__device__ __forceinline__ void split8(const float* f, uint4& h4, uint4& l4) {
  unsigned hu[8], lu[8];
  #pragma unroll
  for (int i = 0; i < 8; ++i) {
    unsigned u = __builtin_bit_cast(unsigned, f[i]);
    float rh = __builtin_bit_cast(float, u & 0xffff0000u);
    float rl = f[i] - rh;
    hu[i] = u >> 16;
    lu[i] = __builtin_bit_cast(unsigned, rl) >> 16;
  }
  h4 = make_uint4(hu[0] | (hu[1] << 16), hu[2] | (hu[3] << 16),
                  hu[4] | (hu[5] << 16), hu[6] | (hu[7] << 16));
  l4 = make_uint4(lu[0] | (lu[1] << 16), lu[2] | (lu[3] << 16),
                  lu[4] | (lu[5] << 16), lu[6] | (lu[7] << 16));
}
__device__ __forceinline__ void split1(float f, short& hi, short& lo) {
  unsigned u = __builtin_bit_cast(unsigned, f);
  float rh = __builtin_bit_cast(float, u & 0xffff0000u);
  float rl = f - rh;
  hi = (short)(u >> 16);
  lo = (short)(__builtin_bit_cast(unsigned, rl) >> 16);
}

// async stage: this wave's 4KB slice of a 32KB chunk into a ring slot (4 x 1KB)
__device__ __forceinline__ void stage_chunk(short* ldst, const short* gsrc,
                                            int w, int lane) {
  #pragma unroll
  for (int i = 0; i < 4; ++i) {
    int off = (w * 4 + i) * 512;              // shorts; 1KB per call
    __builtin_amdgcn_global_load_lds(
        (const __attribute__((address_space(1))) unsigned int*)(gsrc + off + lane * 8),
        (__attribute__((address_space(3))) unsigned int*)(ldst + off), 16, 0, 0);
  }
}

__global__ void zero_scratch(unsigned* done, double* acc) {
  if (threadIdx.x < 256) done[threadIdx.x] = 0u;
  if (threadIdx.x < 8) acc[threadIdx.x] = 0.0;
}

// init rows fp32 -> bf16 hi/lo pair arrays
__global__ void init_convert(const float* __restrict__ src,
                             unsigned short* __restrict__ vh,
                             unsigned short* __restrict__ vl) {
  int slot = blockIdx.x * blockDim.x + threadIdx.x;
  float f[8];
  *(float4*)&f[0] = reinterpret_cast<const float4*>(src)[slot * 2];
  *(float4*)&f[4] = reinterpret_cast<const float4*>(src)[slot * 2 + 1];
  uint4 h4, l4;
  split8(f, h4, l4);
  *(uint4*)(vh + (size_t)slot * 8) = h4;
  *(uint4*)(vl + (size_t)slot * 8) = l4;
}

// ---- one-time W split into MFMA fragment layout ----
__global__ __launch_bounds__(512)
void presplit(const float* __restrict__ W1, const float* __restrict__ W2,
              short* __restrict__ Ws)
{
  const int blk = blockIdx.x;           // r*24 + c
  const int r = blk / 24, c = blk % 24;
  const float* src; int kbase;
  if (c < 16) { src = W1 + (size_t)r * TWOE * EMB; kbase = c * 32; }
  else        { src = W2 + (size_t)r * EMB * EMB;  kbase = (c - 16) * 32; }
  short* dst = Ws + (size_t)blk * CHK_SH;
  const int tid = threadIdx.x;
  #pragma unroll
  for (int u = 0; u < 2; ++u) {
    int qq = tid + u * 512;
    int g = qq >> 6, l = qq & 63;
    const float* p = src + (size_t)(kbase + ((l >> 4) << 3)) * EMB + (g << 4) + (l & 15);
    float f[8];
    #pragma unroll
    for (int i = 0; i < 8; ++i) f[i] = p[i * EMB];
    uint4 h4, l4;
    split8(f, h4, l4);
    *(uint4*)(dst + (size_t)qq * 8) = h4;
    *(uint4*)(dst + 8192 + (size_t)qq * 8) = l4;
  }
}

// ---- fused prepass: levels (LDS) + (level,rule) bucketing + tiles-per-level ----
__global__ __launch_bounds__(1024)
void prepass(const int* __restrict__ pars, const int* __restrict__ rules,
             int* __restrict__ kcnt, int* __restrict__ kofs,
             int* __restrict__ brows, int* __restrict__ tpl, int* __restrict__ nlp)
{
  __shared__ unsigned char slvl[TOTAL];   // 129KB
  __shared__ int scnt[NKEY];              // 8KB
  __shared__ int sofs[NKEY];              // 8KB
  __shared__ int swmax[16];
  const int t = threadIdx.x;
  for (int i = t; i < NINIT; i += 1024) slvl[i] = 0;
  for (int k = t; k < NKEY; k += 1024) scnt[k] = 0;
  __syncthreads();
  int Pa[8], Pb[8];
  if (t < NPS) {
    #pragma unroll
    for (int w = 0; w < 8; ++w) {
      Pa[w] = pars[2 * (w * NPS + t)];
      Pb[w] = pars[2 * (w * NPS + t) + 1];
    }
  }
  int lmax = 0;
  for (int s0 = 0; s0 < NSTEP; s0 += 8) {
    int Na[8], Nb[8];
    if (t < NPS && s0 + 8 < NSTEP) {
      #pragma unroll
      for (int w = 0; w < 8; ++w) {
        Na[w] = pars[2 * ((s0 + 8 + w) * NPS + t)];
        Nb[w] = pars[2 * ((s0 + 8 + w) * NPS + t) + 1];
      }
    }
    #pragma unroll
    for (int w = 0; w < 8; ++w) {
      if (t < NPS) {
        int l1 = slvl[Pa[w]], l2 = slvl[Pb[w]];
        int lv = 1 + (l1 > l2 ? l1 : l2);
        slvl[NINIT + (s0 + w) * NPS + t] = (unsigned char)lv;
        if (lv > lmax) lmax = lv;
      }
      __syncthreads();
    }
    if (t < NPS && s0 + 8 < NSTEP) {
      #pragma unroll
      for (int w = 0; w < 8; ++w) { Pa[w] = Na[w]; Pb[w] = Nb[w]; }
    }
  }
  for (int o = 32; o; o >>= 1) lmax = max(lmax, __shfl_down(lmax, o));
  if ((t & 63) == 0) swmax[t >> 6] = lmax;
  __syncthreads();
  if (t == 0) {
    int m = 0;
    for (int w = 0; w < 16; ++w) m = max(m, swmax[w]);
    nlp[0] = m;
  }
  for (int i = t; i < NNODE; i += 1024) {
    int key = (int)slvl[NINIT + i] * 8 + rules[i >> 8];
    atomicAdd(&scnt[key], 1);
  }
  __syncthreads();
  if (t == 0) {
    int run = 0;
    for (int k = 0; k < NKEY; ++k) {
      sofs[k] = run; kofs[k] = run; kcnt[k] = scnt[k]; run += scnt[k];
    }
  }
  __syncthreads();
  if (t < 256) {
    int s = 0;
    #pragma unroll
    for (int r = 0; r < 8; ++r) s += (scnt[t * 8 + r] + TROWS - 1) >> 5;
    tpl[t] = s;
  }
  for (int i = t; i < NNODE; i += 1024) {
    int key = (int)slvl[NINIT + i] * 8 + rules[i >> 8];
    int pos = atomicAdd(&sofs[key], 1);
    brows[pos] = i;
  }
}

// ---- level-gated scan: async-LDS 3-slot ring, counted vmcnt, raw barriers ----
// Tile 32x256. 8 waves: rw=w&1 (16-row half), cw=w>>1 (64-col strip, 4 frags).
__global__ __launch_bounds__(BTH, 1)
void scan_kernel(const short* __restrict__ Ws, const float* __restrict__ b1,
                 const float* __restrict__ b2, const int* __restrict__ pars,
                 unsigned short* __restrict__ vech, unsigned short* __restrict__ vecl,
                 const int* __restrict__ kcnt, const int* __restrict__ kofs,
                 const int* __restrict__ brows, const int* __restrict__ tpl,
                 const int* __restrict__ nlp, unsigned* __restrict__ done)
{
  __shared__ short wR[3][CHK_SH];    // 96KB: 3-slot W chunk ring (frag layout)
  __shared__ short hH[TROWS][264];   // 16.9KB h hi
  __shared__ short hLo[TROWS][264];  // 16.9KB h lo
  __shared__ int spar[2 * TROWS];
  __shared__ int sorow[TROWS];
  const int tid = threadIdx.x;
  const int bid = blockIdx.x;
  const int lane = tid & 63;
  const int w = tid >> 6;
  const int rw = w & 1, cwb = (w >> 1) << 2;
  const int row16 = lane & 15, kb8 = (lane >> 4) << 3;
  const int arow = (rw << 4) + row16;
  const int hrow = (rw << 4) + ((lane >> 4) << 2);
  const int NL = nlp[0];
  const int xcd = bid & 7, jb = bid >> 3;

  for (int lv = 1; lv <= NL; ++lv) {
    if (tid == 0 && lv > 1) {
      const unsigned need = (unsigned)tpl[lv - 1];
      const unsigned* dp = done + (lv - 1);
      while (load_dev_u32(dp) < need) __builtin_amdgcn_s_sleep(2);
    }
    __syncthreads();
    int cum[9]; cum[0] = 0;
    int cnts[8], ofss[8];
    #pragma unroll
    for (int r = 0; r < 8; ++r) {
      int c = kcnt[lv * 8 + r];
      cnts[r] = c; ofss[r] = kofs[lv * 8 + r];
      cum[r + 1] = cum[r] + ((c + TROWS - 1) >> 5);
    }
    const int G = cum[8];
    const int q = G >> 3, rm = G & 7;
    const int Gx = q + (xcd < rm ? 1 : 0);
    const int sx = xcd * q + (xcd < rm ? xcd : rm);   // bijective XCD swizzle
    for (int j = jb; j < Gx; j += 32) {
      const int g = sx + j;
      int rr = 0;
      while (g >= cum[rr + 1]) ++rr;
      const int t0 = g - cum[rr];
      const int cnt_b = cnts[rr], ofs_b = ofss[rr];
      const int tbase = t0 * TROWS;
      const short* __restrict__ Wr = Ws + (size_t)rr * RULE_SH;

      __syncthreads();   // (A) prev tile fully done with wR/hH/hLo/spar
      // async stage chunks 0,1 (slots 0,1) — independent of spar
      stage_chunk(&wR[0][0], Wr, w, lane);
      stage_chunk(&wR[1][0], Wr + CHK_SH, w, lane);
      if (tid < 2 * TROWS) {
        int slot = tbase + (tid >> 1);
        if (slot >= cnt_b) slot = cnt_b - 1;
        int node = brows[ofs_b + slot];
        spar[tid] = pars[2 * node + (tid & 1)];
        if ((tid & 1) == 0) sorow[tid >> 1] = NINIT + node;
      }
      __syncthreads();   // (B) spar visible
      const int par0 = spar[2 * arow], par1 = spar[2 * arow + 1];
      float b1v[4], b2v[4];
      #pragma unroll
      for (int g4 = 0; g4 < 4; ++g4) {
        b1v[g4] = b1[rr * EMB + ((cwb + g4) << 4) + row16];
        b2v[g4] = b2[rr * EMB + ((cwb + g4) << 4) + row16];
      }
      // A pipeline: 3 deep (chunks 0,1,2)
      uint4 ah[3], al[3];
      #pragma unroll
      for (int d = 0; d < 3; ++d) {
        int kg = d * 32 + kb8;
        int par = (kg >> 8) ? par1 : par0;
        size_t off = (size_t)par * EMB + (kg & 255);
        ah[d] = *(const uint4*)(vech + off);
        al[d] = *(const uint4*)(vecl + off);
      }
      f32x4 acc[4]  = {{0,0,0,0},{0,0,0,0},{0,0,0,0},{0,0,0,0}};
      f32x4 acc2[4] = {{0,0,0,0},{0,0,0,0},{0,0,0,0},{0,0,0,0}};
      // ---- unified 24-chunk loop: counted vmcnt, raw barriers ----
      // issue trace/wave: pro: S0(4) S1(4) A0..A2(6); iter c: S(c+2)(4), A(c+3)(2)
      #pragma unroll
      for (int cc = 0; cc < 24; ++cc) {
        {
          const int n = (cc == 0) ? 10 : (cc == 1) ? 12 :
                        (cc <= 13) ? 8 : (cc == 14) ? 6 : (cc <= 22) ? 4 : 0;
          wait_vm_lgkm(n);                 // own stage(cc) slice + ds ops done
        }
        __builtin_amdgcn_s_barrier();      // all waves' slices of chunk cc ready
        // issue next stage + next A first (in flight across coming barriers)
        if (cc + 2 < 24)
          stage_chunk(&wR[(cc + 2) % 3][0], Wr + (size_t)(cc + 2) * CHK_SH, w, lane);
        if (cc + 3 <= 15) {
          int d = (cc + 3) % 3;
          int kg = (cc + 3) * 32 + kb8;
          int par = (kg >> 8) ? par1 : par0;
          size_t off = (size_t)par * EMB + (kg & 255);
          ah[d] = *(const uint4*)(vech + off);
          al[d] = *(const uint4*)(vecl + off);
        }
        if (cc < 16) {
          s16x8 Ah = __builtin_bit_cast(s16x8, ah[cc % 3]);
          s16x8 Al = __builtin_bit_cast(s16x8, al[cc % 3]);
          #pragma unroll
          for (int g4 = 0; g4 < 4; ++g4) {
            int gi = (cwb + g4) * 64 + lane;
            s16x8 Bh = *(const s16x8*)&wR[cc % 3][gi * 8];
            s16x8 Bl = *(const s16x8*)&wR[cc % 3][8192 + gi * 8];
            acc[g4] = __builtin_amdgcn_mfma_f32_16x16x32_bf16(Ah, Bh, acc[g4], 0, 0, 0);
            acc[g4] = __builtin_amdgcn_mfma_f32_16x16x32_bf16(Ah, Bl, acc[g4], 0, 0, 0);
            acc[g4] = __builtin_amdgcn_mfma_f32_16x16x32_bf16(Al, Bh, acc[g4], 0, 0, 0);
          }
          if (cc == 15) {
            // h = relu(acc + b1) split into hH/hLo (reads at cc>=16 after barrier)
            #pragma unroll
            for (int g4 = 0; g4 < 4; ++g4) {
              #pragma unroll
              for (int jj = 0; jj < 4; ++jj) {
                int col = ((cwb + g4) << 4) + row16;
                short hi, lo;
                split1(fmaxf(acc[g4][jj] + b1v[g4], 0.f), hi, lo);
                hH[hrow + jj][col] = hi; hLo[hrow + jj][col] = lo;
              }
            }
          }
        } else {
          const int kc = (cc - 16) * 32 + kb8;
          s16x8 Ah = *(const s16x8*)&hH[arow][kc];
          s16x8 Al = *(const s16x8*)&hLo[arow][kc];
          #pragma unroll
          for (int g4 = 0; g4 < 4; ++g4) {
            int gi = (cwb + g4) * 64 + lane;
            s16x8 Bh = *(const s16x8*)&wR[cc % 3][gi * 8];
            s16x8 Bl = *(const s16x8*)&wR[cc % 3][8192 + gi * 8];
            acc2[g4] = __builtin_amdgcn_mfma_f32_16x16x32_bf16(Ah, Bh, acc2[g4], 0, 0, 0);
            acc2[g4] = __builtin_amdgcn_mfma_f32_16x16x32_bf16(Ah, Bl, acc2[g4], 0, 0, 0);
            acc2[g4] = __builtin_amdgcn_mfma_f32_16x16x32_bf16(Al, Bh, acc2[g4], 0, 0, 0);
          }
        }
      }
      __syncthreads();   // (D) all hH/hLo A-reads done (full drain OK once/tile)
      // out split -> hH/hLo
      #pragma unroll
      for (int g4 = 0; g4 < 4; ++g4) {
        #pragma unroll
        for (int jj = 0; jj < 4; ++jj) {
          int col = ((cwb + g4) << 4) + row16;
          short hi, lo;
          split1(acc2[g4][jj] + b2v[g4], hi, lo);
          hH[hrow + jj][col] = hi; hLo[hrow + jj][col] = lo;
        }
      }
      __syncthreads();   // (E) out ready
      // coherent stores, guarded for partial tiles (32 rows x 32 col-groups)
      #pragma unroll
      for (int u = 0; u < 2; ++u) {
        int s = tid + u * 512;
        int row = s >> 5, c8 = (s & 31) * 8;
        uint4 h4 = *(const uint4*)&hH[row][c8];
        uint4 l4 = *(const uint4*)&hLo[row][c8];
        if (tbase + row < cnt_b) {
          size_t off = (size_t)sorow[row] * EMB + c8;
          store_dev_b128(vech + off, h4);
          store_dev_b128(vecl + off, l4);
        }
      }
      // ---- publish tile ----
      asm volatile("s_waitcnt vmcnt(0)" ::: "memory");
      __syncthreads();
      if (tid == 0)
        __hip_atomic_fetch_add(done + lv, 1u, __ATOMIC_RELAXED, __HIP_MEMORY_SCOPE_AGENT);
    }
  }
}

__global__ void reduce_pn(const float* __restrict__ pos, const float* __restrict__ neg,
                          double* acc) {
  double sp = 0.0, sn = 0.0;
  for (int m = blockIdx.x * blockDim.x + threadIdx.x; m < MM; m += gridDim.x * blockDim.x) {
    sp += (double)pos[m]; sn += (double)neg[m];
  }
  for (int o = 32; o; o >>= 1) { sp += __shfl_down(sp, o); sn += __shfl_down(sn, o); }
  __shared__ double rp[4], rn[4];
  int wid = threadIdx.x >> 6, lane = threadIdx.x & 63;
  if (lane == 0) { rp[wid] = sp; rn[wid] = sn; }
  __syncthreads();
  if (threadIdx.x == 0) {
    double tp = 0.0, tn = 0.0;
    for (int w = 0; w < 4; ++w) { tp += rp[w]; tn += rn[w]; }
    atomicAdd(&acc[0], tp); atomicAdd(&acc[1], tn);
  }
}

__global__ __launch_bounds__(256)
void eval_kernel(const unsigned short* __restrict__ vh, const unsigned short* __restrict__ vl,
                 const int* __restrict__ mask,
                 const float* __restrict__ eW1, const float* __restrict__ eb1,
                 const float* __restrict__ eW2, const float* __restrict__ eb2,
                 float* __restrict__ val)
{
  __shared__ float xL[64][36];
  __shared__ float wLx[32][260];
  __shared__ int mrow[64];
  const int tid = threadIdx.x;
  const int a = tid >> 4, b = tid & 15;
  const int m0 = blockIdx.x * 64;
  if (tid < 64) mrow[tid] = mask[m0 + tid];
  __syncthreads();

  float acc[4][16];
  #pragma unroll
  for (int i = 0; i < 4; ++i)
    #pragma unroll
    for (int j = 0; j < 16; ++j) acc[i][j] = 0.f;

  for (int c = 0; c < 8; ++c) {
    const int e0 = c * 32;
    for (int idx = tid; idx < 64 * 4; idx += 256) {
      int rr = idx >> 2, u = idx & 3;
      size_t off = (size_t)mrow[rr] * EMB + e0 + u * 8;
      uint4 hv = *(const uint4*)(vh + off);
      uint4 lv = *(const uint4*)(vl + off);
      const unsigned* hu = (const unsigned*)&hv;
      const unsigned* lu = (const unsigned*)&lv;
      float fo[8];
      #pragma unroll
      for (int jj = 0; jj < 4; ++jj) {
        fo[2 * jj] = __builtin_bit_cast(float, (hu[jj] & 0xffffu) << 16) +
                     __builtin_bit_cast(float, (lu[jj] & 0xffffu) << 16);
        fo[2 * jj + 1] = __builtin_bit_cast(float, hu[jj] & 0xffff0000u) +
                         __builtin_bit_cast(float, lu[jj] & 0xffff0000u);
      }
      *(float4*)&xL[rr][u * 8] = *(float4*)&fo[0];
      *(float4*)&xL[rr][u * 8 + 4] = *(float4*)&fo[4];
    }
    for (int idx = tid; idx < 32 * 64; idx += 256) {
      int e = idx >> 6, k4 = idx & 63;
      reinterpret_cast<float4*>(&wLx[e][0])[k4] =
          reinterpret_cast<const float4*>(eW1 + (size_t)(e0 + e) * EMB)[k4];
    }
    __syncthreads();
    #pragma unroll 4
    for (int e = 0; e < 32; ++e) {
      float xs[4];
      #pragma unroll
      for (int rr = 0; rr < 4; ++rr) xs[rr] = xL[a * 4 + rr][e];
      const float4* wr = reinterpret_cast<const float4*>(&wLx[e][0]) + b * 4;
      float wk[16];
      *reinterpret_cast<float4*>(&wk[0])  = wr[0];
      *reinterpret_cast<float4*>(&wk[4])  = wr[1];
      *reinterpret_cast<float4*>(&wk[8])  = wr[2];
      *reinterpret_cast<float4*>(&wk[12]) = wr[3];
      #pragma unroll
      for (int rr = 0; rr < 4; ++rr)
        #pragma unroll
        for (int kk = 0; kk < 16; ++kk)
          acc[rr][kk] = fmaf(xs[rr], wk[kk], acc[rr][kk]);
    }
    __syncthreads();
  }

  float eb2v = eb2[0];
  float pv[4];
  #pragma unroll
  for (int rr = 0; rr < 4; ++rr) {
    float s = 0.f;
    #pragma unroll
    for (int kk = 0; kk < 16; ++kk) {
      float h = acc[rr][kk] + eb1[b * 16 + kk];
      h = fmaxf(h, 0.f);
      s += h * eW2[b * 16 + kk];
    }
    pv[rr] = s;
  }
  #pragma unroll
  for (int m = 1; m < 16; m <<= 1) {
    #pragma unroll
    for (int rr = 0; rr < 4; ++rr) pv[rr] += __shfl_xor(pv[rr], m);
  }
  if (b == 0) {
    #pragma unroll
    for (int rr = 0; rr < 4; ++rr) val[m0 + a * 4 + rr] = pv[rr] + eb2v;
  }
}

// loss (pw computed inline from acc[0], acc[1])
__global__ void loss_kernel(const float* __restrict__ val, const float* __restrict__ pos,
                            const float* __restrict__ neg, const float* __restrict__ tgt,
                            double* acc)
{
  const float pw = (float)(acc[1] / fmax(acc[0], 1.0));
  double l = 0.0, pk = 0.0, nk = 0.0;
  for (int m = blockIdx.x * blockDim.x + threadIdx.x; m < MM; m += gridDim.x * blockDim.x) {
    float v = val[m], p = pos[m], n = neg[m], t = tgt[m];
    float lp = log1pf(expf(-fabsf(v)));
    float spn = fmaxf(-v, 0.f) + lp;
    float spp = fmaxf(v, 0.f) + lp;
    float contrib = pw * t * spn + (1.f - t) * spp;
    l += (double)((p + n) * contrib);
    if (v >= 0.f) pk += (double)p; else nk += (double)n;
  }
  for (int o = 32; o; o >>= 1) {
    l += __shfl_down(l, o); pk += __shfl_down(pk, o); nk += __shfl_down(nk, o);
  }
  __shared__ double s0[4], s1[4], s2[4];
  int wid = threadIdx.x >> 6, lane = threadIdx.x & 63;
  if (lane == 0) { s0[wid] = l; s1[wid] = pk; s2[wid] = nk; }
  __syncthreads();
  if (threadIdx.x == 0) {
    double ta = 0.0, tb = 0.0, tc = 0.0;
    for (int w = 0; w < 4; ++w) { ta += s0[w]; tb += s1[w]; tc += s2[w]; }
    atomicAdd(&acc[2], ta); atomicAdd(&acc[3], tb); atomicAdd(&acc[4], tc);
  }
}

__global__ void writeout(const double* __restrict__ acc, float* __restrict__ out) {
  if (threadIdx.x == 0) {
    out[0] = (float)acc[2];
    out[1] = (float)acc[3];
    out[2] = (float)acc[4];
  }
}

extern "C" void kernel_launch(void* const* d_in, const int* in_sizes, int n_in,
                              void* d_out, int out_size, void* d_ws, size_t ws_size,
                              hipStream_t stream)
{
  (void)in_sizes; (void)n_in; (void)out_size; (void)ws_size;
  const float* init_vecs = (const float*)d_in[0];
  const float* W1  = (const float*)d_in[1];
  const float* b1  = (const float*)d_in[2];
  const float* W2  = (const float*)d_in[3];
  const float* b2  = (const float*)d_in[4];
  const float* eW1 = (const float*)d_in[5];
  const float* eb1 = (const float*)d_in[6];
  const float* eW2 = (const float*)d_in[7];
  const float* eb2 = (const float*)d_in[8];
  const float* pos = (const float*)d_in[9];
  const float* neg = (const float*)d_in[10];
  const float* tgt = (const float*)d_in[11];
  const int* pars  = (const int*)d_in[13];
  const int* rules = (const int*)d_in[14];
  const int* mask  = (const int*)d_in[15];

  char* ws = (char*)d_ws;
  unsigned short* vech = (unsigned short*)(ws + OFF_VECH);
  unsigned short* vecl = (unsigned short*)(ws + OFF_VECL);
  float*    val   = (float*)(ws + OFF_VAL);
  unsigned* done  = (unsigned*)(ws + OFF_CNT);
  double*   acc   = (double*)(ws + OFF_ACC);
  int*      kcnt  = (int*)(ws + OFF_KCNT);
  int*      kofs  = (int*)(ws + OFF_KOFS);
  int*      nlp   = (int*)(ws + OFF_NL);
  int*      tpl   = (int*)(ws + OFF_TPL);
  int*      brows = (int*)(ws + OFF_BROWS);
  short*    Ws    = (short*)(ws + OFF_WSPLIT);

  zero_scratch<<<1, 256, 0, stream>>>(done, acc);
  prepass<<<1, 1024, 0, stream>>>(pars, rules, kcnt, kofs, brows, tpl, nlp);
  init_convert<<<128, 256, 0, stream>>>(init_vecs, vech, vecl);
  presplit<<<192, 512, 0, stream>>>(W1, W2, Ws);
  scan_kernel<<<256, BTH, 0, stream>>>(Ws, b1, b2, pars, vech, vecl,
                                       kcnt, kofs, brows, tpl, nlp, done);
  reduce_pn<<<128, 256, 0, stream>>>(pos, neg, acc);
  eval_kernel<<<1024, 256, 0, stream>>>(vech, vecl, mask, eW1, eb1, eW2, eb2, val);
  loss_kernel<<<128, 256, 0, stream>>>(val, pos, neg, tgt, acc);
  writeout<<<1, 1, 0, stream>>>(acc, (float*)d_out);
}

// Round 19
// 1115.126 us; speedup vs baseline: 1.1337x; 1.1337x over previous
//
#include <hip/hip_runtime.h>
#include <math.h>

#define EMB   256
#define TWOE  512
#define NINIT 1024
#define NSTEP 512
#define NPS   256
#define TOTAL (NINIT + NSTEP * NPS)   // 132096
#define MM    65536
#define NNODE (NSTEP * NPS)           // 131072
#define NKEY  2048                    // 256 levels x 8 rules
#define BTH   512
#define TROWS 32                      // rows per tile
#define CHK_SH  16384                 // shorts per chunk (hi 8192 + lo 8192) = 32KB
#define RULE_SH (24 * CHK_SH)         // 24 chunks per rule (16 W1 + 8 W2)

typedef short s16x8 __attribute__((ext_vector_type(8)));
typedef float f32x4 __attribute__((ext_vector_type(4)));

// ---- workspace layout (bytes) ----
#define OFF_VECH   0ull
#define OFF_VECL   ((size_t)TOTAL * EMB * 2)            // 67633152
#define OFF_VAL    (2ull * (size_t)TOTAL * EMB * 2)     // 135266304
#define OFF_CNT    (OFF_VAL + (size_t)MM * 4)           // done[256]
#define OFF_ACC    (OFF_CNT + 4096)
#define OFF_KCNT   (OFF_ACC + 256)
#define OFF_KOFS   (OFF_KCNT + (size_t)NKEY * 4)
#define OFF_NL     (OFF_KOFS + (size_t)NKEY * 4)
#define OFF_TPL    (OFF_NL + 256)
#define OFF_BROWS  (OFF_TPL + 4096)
#define OFF_WSPLIT (OFF_BROWS + (size_t)NNODE * 4)      // +6291456

// acc layout: [0]=sum(pos) [1]=sum(neg) [2]=loss [3]=posOK [4]=negOK

// ---- coherence-point (bypass L1/L2) ops ----
__device__ __forceinline__ void store_dev_u32(unsigned* p, unsigned v) {
  asm volatile("global_store_dword %0, %1, off sc0 sc1" :: "v"(p), "v"(v) : "memory");
}
__device__ __forceinline__ void store_dev_b64(void* p, uint2 v) {
  asm volatile("global_store_dwordx2 %0, %1, off sc0 sc1" :: "v"(p), "v"(v) : "memory");
}
__device__ __forceinline__ void store_dev_b128(void* p, uint4 v) {
  store_dev_b64(p, make_uint2(v.x, v.y));
  store_dev_b64((char*)p + 8, make_uint2(v.z, v.w));
}
__device__ __forceinline__ unsigned load_dev_u32(const unsigned* p) {
  unsigned r;
  asm volatile("global_load_dword %0, %1, off sc0 sc1\n\ts_waitcnt vmcnt(0)"
               : "=v"(r) : "v"(p) : "memory");
  return r;
}

// split helpers (truncation split f32 -> bf16 hi + bf16 lo)
__device__ __forceinline__ void split8(const float* f, uint4& h4, uint4& l4) {
  unsigned hu[8], lu[8];
  #pragma unroll
  for (int i = 0; i < 8; ++i) {
    unsigned u = __builtin_bit_cast(unsigned, f[i]);
    float rh = __builtin_bit_cast(float, u & 0xffff0000u);
    float rl = f[i] - rh;
    hu[i] = u >> 16;
    lu[i] = __builtin_bit_cast(unsigned, rl) >> 16;
  }
  h4 = make_uint4(hu[0] | (hu[1] << 16), hu[2] | (hu[3] << 16),
                  hu[4] | (hu[5] << 16), hu[6] | (hu[7] << 16));
  l4 = make_uint4(lu[0] | (lu[1] << 16), lu[2] | (lu[3] << 16),
                  lu[4] | (lu[5] << 16), lu[6] | (lu[7] << 16));
}
__device__ __forceinline__ void split1(float f, short& hi, short& lo) {
  unsigned u = __builtin_bit_cast(unsigned, f);
  float rh = __builtin_bit_cast(float, u & 0xffff0000u);
  float rl = f - rh;
  hi = (short)(u >> 16);
  lo = (short)(__builtin_bit_cast(unsigned, rl) >> 16);
}

__global__ void zero_scratch(unsigned* done, double* acc) {
  if (threadIdx.x < 256) done[threadIdx.x] = 0u;
  if (threadIdx.x < 8) acc[threadIdx.x] = 0.0;
}

// init rows fp32 -> bf16 hi/lo pair arrays
__global__ void init_convert(const float* __restrict__ src,
                             unsigned short* __restrict__ vh,
                             unsigned short* __restrict__ vl) {
  int slot = blockIdx.x * blockDim.x + threadIdx.x;
  float f[8];
  *(float4*)&f[0] = reinterpret_cast<const float4*>(src)[slot * 2];
  *(float4*)&f[4] = reinterpret_cast<const float4*>(src)[slot * 2 + 1];
  uint4 h4, l4;
  split8(f, h4, l4);
  *(uint4*)(vh + (size_t)slot * 8) = h4;
  *(uint4*)(vl + (size_t)slot * 8) = l4;
}

// ---- one-time W split into MFMA fragment layout ----
__global__ __launch_bounds__(512)
void presplit(const float* __restrict__ W1, const float* __restrict__ W2,
              short* __restrict__ Ws)
{
  const int blk = blockIdx.x;           // r*24 + c
  const int r = blk / 24, c = blk % 24;
  const float* src; int kbase;
  if (c < 16) { src = W1 + (size_t)r * TWOE * EMB; kbase = c * 32; }
  else        { src = W2 + (size_t)r * EMB * EMB;  kbase = (c - 16) * 32; }
  short* dst = Ws + (size_t)blk * CHK_SH;
  const int tid = threadIdx.x;
  #pragma unroll
  for (int u = 0; u < 2; ++u) {
    int qq = tid + u * 512;
    int g = qq >> 6, l = qq & 63;
    const float* p = src + (size_t)(kbase + ((l >> 4) << 3)) * EMB + (g << 4) + (l & 15);
    float f[8];
    #pragma unroll
    for (int i = 0; i < 8; ++i) f[i] = p[i * EMB];
    uint4 h4, l4;
    split8(f, h4, l4);
    *(uint4*)(dst + (size_t)qq * 8) = h4;
    *(uint4*)(dst + 8192 + (size_t)qq * 8) = l4;
  }
}

// ---- fused prepass: levels (LDS) + (level,rule) bucketing + tiles-per-level ----
__global__ __launch_bounds__(1024)
void prepass(const int* __restrict__ pars, const int* __restrict__ rules,
             int* __restrict__ kcnt, int* __restrict__ kofs,
             int* __restrict__ brows, int* __restrict__ tpl, int* __restrict__ nlp)
{
  __shared__ unsigned char slvl[TOTAL];   // 129KB
  __shared__ int scnt[NKEY];              // 8KB
  __shared__ int sofs[NKEY];              // 8KB
  __shared__ int swmax[16];
  const int t = threadIdx.x;
  for (int i = t; i < NINIT; i += 1024) slvl[i] = 0;
  for (int k = t; k < NKEY; k += 1024) scnt[k] = 0;
  __syncthreads();
  int Pa[8], Pb[8];
  if (t < NPS) {
    #pragma unroll
    for (int w = 0; w < 8; ++w) {
      Pa[w] = pars[2 * (w * NPS + t)];
      Pb[w] = pars[2 * (w * NPS + t) + 1];
    }
  }
  int lmax = 0;
  for (int s0 = 0; s0 < NSTEP; s0 += 8) {
    int Na[8], Nb[8];
    if (t < NPS && s0 + 8 < NSTEP) {
      #pragma unroll
      for (int w = 0; w < 8; ++w) {
        Na[w] = pars[2 * ((s0 + 8 + w) * NPS + t)];
        Nb[w] = pars[2 * ((s0 + 8 + w) * NPS + t) + 1];
      }
    }
    #pragma unroll
    for (int w = 0; w < 8; ++w) {
      if (t < NPS) {
        int l1 = slvl[Pa[w]], l2 = slvl[Pb[w]];
        int lv = 1 + (l1 > l2 ? l1 : l2);
        slvl[NINIT + (s0 + w) * NPS + t] = (unsigned char)lv;
        if (lv > lmax) lmax = lv;
      }
      __syncthreads();
    }
    if (t < NPS && s0 + 8 < NSTEP) {
      #pragma unroll
      for (int w = 0; w < 8; ++w) { Pa[w] = Na[w]; Pb[w] = Nb[w]; }
    }
  }
  for (int o = 32; o; o >>= 1) lmax = max(lmax, __shfl_down(lmax, o));
  if ((t & 63) == 0) swmax[t >> 6] = lmax;
  __syncthreads();
  if (t == 0) {
    int m = 0;
    for (int w = 0; w < 16; ++w) m = max(m, swmax[w]);
    nlp[0] = m;
  }
  for (int i = t; i < NNODE; i += 1024) {
    int key = (int)slvl[NINIT + i] * 8 + rules[i >> 8];
    atomicAdd(&scnt[key], 1);
  }
  __syncthreads();
  if (t == 0) {
    int run = 0;
    for (int k = 0; k < NKEY; ++k) {
      sofs[k] = run; kofs[k] = run; kcnt[k] = scnt[k]; run += scnt[k];
    }
  }
  __syncthreads();
  if (t < 256) {
    int s = 0;
    #pragma unroll
    for (int r = 0; r < 8; ++r) s += (scnt[t * 8 + r] + TROWS - 1) >> 5;
    tpl[t] = s;
  }
  for (int i = t; i < NNODE; i += 1024) {
    int key = (int)slvl[NINIT + i] * 8 + rules[i >> 8];
    int pos = atomicAdd(&sofs[key], 1);
    brows[pos] = i;
  }
}

#define LOADW(S0, S1, S2, S3, ch) { \
  const short* cs_ = Wr + (size_t)(ch) * CHK_SH; \
  S0 = *(const uint4*)(cs_ + (size_t)tid * 8); \
  S1 = *(const uint4*)(cs_ + (size_t)(512 + tid) * 8); \
  S2 = *(const uint4*)(cs_ + 8192 + (size_t)tid * 8); \
  S3 = *(const uint4*)(cs_ + 8192 + (size_t)(512 + tid) * 8); }
#define WRITEW(buf, S0, S1, S2, S3) { \
  *(uint4*)&wB[buf][tid * 8] = S0; \
  *(uint4*)&wB[buf][(512 + tid) * 8] = S1; \
  *(uint4*)&wB[buf][8192 + tid * 8] = S2; \
  *(uint4*)&wB[buf][8192 + (512 + tid) * 8] = S3; }

// ---- level-gated scan: presplit-W 2-deep reg pipeline, split-bf16 MFMA ----
// Tile 32x256. 8 waves: rw=w&1 (16-row half), cw=w>>1 (64-col strip, 4 frags).
__global__ __launch_bounds__(BTH, 1)
void scan_kernel(const short* __restrict__ Ws, const float* __restrict__ b1,
                 const float* __restrict__ b2, const int* __restrict__ pars,
                 unsigned short* __restrict__ vech, unsigned short* __restrict__ vecl,
                 const int* __restrict__ kcnt, const int* __restrict__ kofs,
                 const int* __restrict__ brows, const int* __restrict__ tpl,
                 const int* __restrict__ nlp, unsigned* __restrict__ done)
{
  __shared__ short wB[2][CHK_SH];    // 64KB W chunk double-buffer (frag layout)
  __shared__ short hH[TROWS][264];   // 16.9KB h hi
  __shared__ short hLo[TROWS][264];  // 16.9KB h lo
  __shared__ int spar[2 * TROWS];
  __shared__ int sorow[TROWS];
  const int tid = threadIdx.x;
  const int bid = blockIdx.x;
  const int lane = tid & 63;
  const int w = tid >> 6;
  const int rw = w & 1, cwb = (w >> 1) << 2;
  const int row16 = lane & 15, kb8 = (lane >> 4) << 3;
  const int arow = (rw << 4) + row16;
  const int hrow = (rw << 4) + ((lane >> 4) << 2);
  const int NL = nlp[0];
  const int xcd = bid & 7, jb = bid >> 3;

  for (int lv = 1; lv <= NL; ++lv) {
    if (tid == 0 && lv > 1) {
      const unsigned need = (unsigned)tpl[lv - 1];
      const unsigned* dp = done + (lv - 1);
      while (load_dev_u32(dp) < need) __builtin_amdgcn_s_sleep(2);
    }
    __syncthreads();
    int cum[9]; cum[0] = 0;
    int cnts[8], ofss[8];
    #pragma unroll
    for (int r = 0; r < 8; ++r) {
      int c = kcnt[lv * 8 + r];
      cnts[r] = c; ofss[r] = kofs[lv * 8 + r];
      cum[r + 1] = cum[r] + ((c + TROWS - 1) >> 5);
    }
    const int G = cum[8];
    const int q = G >> 3, rm = G & 7;
    const int Gx = q + (xcd < rm ? 1 : 0);
    const int sx = xcd * q + (xcd < rm ? xcd : rm);   // bijective XCD swizzle
    for (int j = jb; j < Gx; j += 32) {
      const int g = sx + j;
      int rr = 0;
      while (g >= cum[rr + 1]) ++rr;
      const int t0 = g - cum[rr];
      const int cnt_b = cnts[rr], ofs_b = ofss[rr];
      const int tbase = t0 * TROWS;
      const short* __restrict__ Wr = Ws + (size_t)rr * RULE_SH;

      __syncthreads();   // (A) prev tile fully done with wB/hH/hLo/spar
      if (tid < 2 * TROWS) {
        int slot = tbase + (tid >> 1);
        if (slot >= cnt_b) slot = cnt_b - 1;
        int node = brows[ofs_b + slot];
        spar[tid] = pars[2 * node + (tid & 1)];
        if ((tid & 1) == 0) sorow[tid >> 1] = NINIT + node;
      }
      // stage W chunk 0 into reg set A (overlaps spar LDS writes)
      uint4 sA0, sA1, sA2, sA3, sB0, sB1, sB2, sB3;
      LOADW(sA0, sA1, sA2, sA3, 0);
      __syncthreads();   // (B) spar visible
      const int par0 = spar[2 * arow], par1 = spar[2 * arow + 1];
      float b1v[4], b2v[4];
      #pragma unroll
      for (int g4 = 0; g4 < 4; ++g4) {
        b1v[g4] = b1[rr * EMB + ((cwb + g4) << 4) + row16];
        b2v[g4] = b2[rr * EMB + ((cwb + g4) << 4) + row16];
      }
      // A pipeline: 3 deep (chunks 0,1,2)
      uint4 ah[3], al[3];
      #pragma unroll
      for (int d = 0; d < 3; ++d) {
        int kg = d * 32 + kb8;
        int par = (kg >> 8) ? par1 : par0;
        size_t off = (size_t)par * EMB + (kg & 255);
        ah[d] = *(const uint4*)(vech + off);
        al[d] = *(const uint4*)(vecl + off);
      }
      WRITEW(0, sA0, sA1, sA2, sA3);   // chunk 0 -> wB[0] (waits chunk-0 loads)
      LOADW(sB0, sB1, sB2, sB3, 1);    // chunk 1 -> reg set B
      __syncthreads();   // (C) wB[0] ready
      f32x4 acc[4]  = {{0,0,0,0},{0,0,0,0},{0,0,0,0},{0,0,0,0}};
      f32x4 acc2[4] = {{0,0,0,0},{0,0,0,0},{0,0,0,0},{0,0,0,0}};
      // ---- unified 24-chunk loop, fully unrolled, 2-deep W / 3-deep A ----
      #pragma unroll
      for (int cc = 0; cc < 24; ++cc) {
        if (cc < 16) {
          s16x8 Ah = __builtin_bit_cast(s16x8, ah[cc % 3]);
          s16x8 Al = __builtin_bit_cast(s16x8, al[cc % 3]);
          #pragma unroll
          for (int g4 = 0; g4 < 4; ++g4) {
            int gi = (cwb + g4) * 64 + lane;
            s16x8 Bh = *(const s16x8*)&wB[cc & 1][gi * 8];
            s16x8 Bl = *(const s16x8*)&wB[cc & 1][8192 + gi * 8];
            acc[g4] = __builtin_amdgcn_mfma_f32_16x16x32_bf16(Ah, Bh, acc[g4], 0, 0, 0);
            acc[g4] = __builtin_amdgcn_mfma_f32_16x16x32_bf16(Ah, Bl, acc[g4], 0, 0, 0);
            acc[g4] = __builtin_amdgcn_mfma_f32_16x16x32_bf16(Al, Bh, acc[g4], 0, 0, 0);
          }
        } else {
          const int kc = (cc - 16) * 32 + kb8;
          s16x8 Ah = *(const s16x8*)&hH[arow][kc];
          s16x8 Al = *(const s16x8*)&hLo[arow][kc];
          #pragma unroll
          for (int g4 = 0; g4 < 4; ++g4) {
            int gi = (cwb + g4) * 64 + lane;
            s16x8 Bh = *(const s16x8*)&wB[cc & 1][gi * 8];
            s16x8 Bl = *(const s16x8*)&wB[cc & 1][8192 + gi * 8];
            acc2[g4] = __builtin_amdgcn_mfma_f32_16x16x32_bf16(Ah, Bh, acc2[g4], 0, 0, 0);
            acc2[g4] = __builtin_amdgcn_mfma_f32_16x16x32_bf16(Ah, Bl, acc2[g4], 0, 0, 0);
            acc2[g4] = __builtin_amdgcn_mfma_f32_16x16x32_bf16(Al, Bh, acc2[g4], 0, 0, 0);
          }
        }
        if (cc == 15) {
          // h = relu(acc + b1) split into hH/hLo
          #pragma unroll
          for (int g4 = 0; g4 < 4; ++g4) {
            #pragma unroll
            for (int jj = 0; jj < 4; ++jj) {
              int col = ((cwb + g4) << 4) + row16;
              short hi, lo;
              split1(fmaxf(acc[g4][jj] + b1v[g4], 0.f), hi, lo);
              hH[hrow + jj][col] = hi; hLo[hrow + jj][col] = lo;
            }
          }
        }
        if (cc < 23) {
          // write chunk cc+1 (regs loaded at iter cc-1) into wB[(cc+1)&1]
          if (((cc + 1) & 1) == 0) { WRITEW(0, sA0, sA1, sA2, sA3); }
          else                     { WRITEW(1, sB0, sB1, sB2, sB3); }
        }
        if (cc < 22) {
          // issue loads for chunk cc+2 into the just-freed reg set
          if (((cc + 2) & 1) == 0) { LOADW(sA0, sA1, sA2, sA3, cc + 2); }
          else                     { LOADW(sB0, sB1, sB2, sB3, cc + 2); }
        }
        if (cc + 3 <= 15) {
          int d = (cc + 3) % 3;
          int kg = (cc + 3) * 32 + kb8;
          int par = (kg >> 8) ? par1 : par0;
          size_t off = (size_t)par * EMB + (kg & 255);
          ah[d] = *(const uint4*)(vech + off);
          al[d] = *(const uint4*)(vecl + off);
        }
        __syncthreads();
      }
      // out split -> hH/hLo
      #pragma unroll
      for (int g4 = 0; g4 < 4; ++g4) {
        #pragma unroll
        for (int jj = 0; jj < 4; ++jj) {
          int col = ((cwb + g4) << 4) + row16;
          short hi, lo;
          split1(acc2[g4][jj] + b2v[g4], hi, lo);
          hH[hrow + jj][col] = hi; hLo[hrow + jj][col] = lo;
        }
      }
      __syncthreads();   // (E) out ready
      // coherent stores, guarded for partial tiles (32 rows x 32 col-groups)
      #pragma unroll
      for (int u = 0; u < 2; ++u) {
        int s = tid + u * 512;
        int row = s >> 5, c8 = (s & 31) * 8;
        uint4 h4 = *(const uint4*)&hH[row][c8];
        uint4 l4 = *(const uint4*)&hLo[row][c8];
        if (tbase + row < cnt_b) {
          size_t off = (size_t)sorow[row] * EMB + c8;
          store_dev_b128(vech + off, h4);
          store_dev_b128(vecl + off, l4);
        }
      }
      // ---- publish tile ----
      asm volatile("s_waitcnt vmcnt(0)" ::: "memory");
      __syncthreads();
      if (tid == 0)
        __hip_atomic_fetch_add(done + lv, 1u, __ATOMIC_RELAXED, __HIP_MEMORY_SCOPE_AGENT);
    }
  }
}

__global__ void reduce_pn(const float* __restrict__ pos, const float* __restrict__ neg,
                          double* acc) {
  double sp = 0.0, sn = 0.0;
  for (int m = blockIdx.x * blockDim.x + threadIdx.x; m < MM; m += gridDim.x * blockDim.x) {
    sp += (double)pos[m]; sn += (double)neg[m];
  }
  for (int o = 32; o; o >>= 1) { sp += __shfl_down(sp, o); sn += __shfl_down(sn, o); }
  __shared__ double rp[4], rn[4];
  int wid = threadIdx.x >> 6, lane = threadIdx.x & 63;
  if (lane == 0) { rp[wid] = sp; rn[wid] = sn; }
  __syncthreads();
  if (threadIdx.x == 0) {
    double tp = 0.0, tn = 0.0;
    for (int w = 0; w < 4; ++w) { tp += rp[w]; tn += rn[w]; }
    atomicAdd(&acc[0], tp); atomicAdd(&acc[1], tn);
  }
}

__global__ __launch_bounds__(256)
void eval_kernel(const unsigned short* __restrict__ vh, const unsigned short* __restrict__ vl,
                 const int* __restrict__ mask,
                 const float* __restrict__ eW1, const float* __restrict__ eb1,
                 const float* __restrict__ eW2, const float* __restrict__ eb2,
                 float* __restrict__ val)
{
  __shared__ float xL[64][36];
  __shared__ float wLx[32][260];
  __shared__ int mrow[64];
  const int tid = threadIdx.x;
  const int a = tid >> 4, b = tid & 15;
  const int m0 = blockIdx.x * 64;
  if (tid < 64) mrow[tid] = mask[m0 + tid];
  __syncthreads();

  float acc[4][16];
  #pragma unroll
  for (int i = 0; i < 4; ++i)
    #pragma unroll
    for (int j = 0; j < 16; ++j) acc[i][j] = 0.f;

  for (int c = 0; c < 8; ++c) {
    const int e0 = c * 32;
    for (int idx = tid; idx < 64 * 4; idx += 256) {
      int rr = idx >> 2, u = idx & 3;
      size_t off = (size_t)mrow[rr] * EMB + e0 + u * 8;
      uint4 hv = *(const uint4*)(vh + off);
      uint4 lv = *(const uint4*)(vl + off);
      const unsigned* hu = (const unsigned*)&hv;
      const unsigned* lu = (const unsigned*)&lv;
      float fo[8];
      #pragma unroll
      for (int jj = 0; jj < 4; ++jj) {
        fo[2 * jj] = __builtin_bit_cast(float, (hu[jj] & 0xffffu) << 16) +
                     __builtin_bit_cast(float, (lu[jj] & 0xffffu) << 16);
        fo[2 * jj + 1] = __builtin_bit_cast(float, hu[jj] & 0xffff0000u) +
                         __builtin_bit_cast(float, lu[jj] & 0xffff0000u);
      }
      *(float4*)&xL[rr][u * 8] = *(float4*)&fo[0];
      *(float4*)&xL[rr][u * 8 + 4] = *(float4*)&fo[4];
    }
    for (int idx = tid; idx < 32 * 64; idx += 256) {
      int e = idx >> 6, k4 = idx & 63;
      reinterpret_cast<float4*>(&wLx[e][0])[k4] =
          reinterpret_cast<const float4*>(eW1 + (size_t)(e0 + e) * EMB)[k4];
    }
    __syncthreads();
    #pragma unroll 4
    for (int e = 0; e < 32; ++e) {
      float xs[4];
      #pragma unroll
      for (int rr = 0; rr < 4; ++rr) xs[rr] = xL[a * 4 + rr][e];
      const float4* wr = reinterpret_cast<const float4*>(&wLx[e][0]) + b * 4;
      float wk[16];
      *reinterpret_cast<float4*>(&wk[0])  = wr[0];
      *reinterpret_cast<float4*>(&wk[4])  = wr[1];
      *reinterpret_cast<float4*>(&wk[8])  = wr[2];
      *reinterpret_cast<float4*>(&wk[12]) = wr[3];
      #pragma unroll
      for (int rr = 0; rr < 4; ++rr)
        #pragma unroll
        for (int kk = 0; kk < 16; ++kk)
          acc[rr][kk] = fmaf(xs[rr], wk[kk], acc[rr][kk]);
    }
    __syncthreads();
  }

  float eb2v = eb2[0];
  float pv[4];
  #pragma unroll
  for (int rr = 0; rr < 4; ++rr) {
    float s = 0.f;
    #pragma unroll
    for (int kk = 0; kk < 16; ++kk) {
      float h = acc[rr][kk] + eb1[b * 16 + kk];
      h = fmaxf(h, 0.f);
      s += h * eW2[b * 16 + kk];
    }
    pv[rr] = s;
  }
  #pragma unroll
  for (int m = 1; m < 16; m <<= 1) {
    #pragma unroll
    for (int rr = 0; rr < 4; ++rr) pv[rr] += __shfl_xor(pv[rr], m);
  }
  if (b == 0) {
    #pragma unroll
    for (int rr = 0; rr < 4; ++rr) val[m0 + a * 4 + rr] = pv[rr] + eb2v;
  }
}

// loss (pw computed inline from acc[0], acc[1])
__global__ void loss_kernel(const float* __restrict__ val, const float* __restrict__ pos,
                            const float* __restrict__ neg, const float* __restrict__ tgt,
                            double* acc)
{
  const float pw = (float)(acc[1] / fmax(acc[0], 1.0));
  double l = 0.0, pk = 0.0, nk = 0.0;
  for (int m = blockIdx.x * blockDim.x + threadIdx.x; m < MM; m += gridDim.x * blockDim.x) {
    float v = val[m], p = pos[m], n = neg[m], t = tgt[m];
    float lp = log1pf(expf(-fabsf(v)));
    float spn = fmaxf(-v, 0.f) + lp;
    float spp = fmaxf(v, 0.f) + lp;
    float contrib = pw * t * spn + (1.f - t) * spp;
    l += (double)((p + n) * contrib);
    if (v >= 0.f) pk += (double)p; else nk += (double)n;
  }
  for (int o = 32; o; o >>= 1) {
    l += __shfl_down(l, o); pk += __shfl_down(pk, o); nk += __shfl_down(nk, o);
  }
  __shared__ double s0[4], s1[4], s2[4];
  int wid = threadIdx.x >> 6, lane = threadIdx.x & 63;
  if (lane == 0) { s0[wid] = l; s1[wid] = pk; s2[wid] = nk; }
  __syncthreads();
  if (threadIdx.x == 0) {
    double ta = 0.0, tb = 0.0, tc = 0.0;
    for (int w = 0; w < 4; ++w) { ta += s0[w]; tb += s1[w]; tc += s2[w]; }
    atomicAdd(&acc[2], ta); atomicAdd(&acc[3], tb); atomicAdd(&acc[4], tc);
  }
}

__global__ void writeout(const double* __restrict__ acc, float* __restrict__ out) {
  if (threadIdx.x == 0) {
    out[0] = (float)acc[2];
    out[1] = (float)acc[3];
    out[2] = (float)acc[4];
  }
}

extern "C" void kernel_launch(void* const* d_in, const int* in_sizes, int n_in,
                              void* d_out, int out_size, void* d_ws, size_t ws_size,
                              hipStream_t stream)
{
  (void)in_sizes; (void)n_in; (void)out_size; (void)ws_size;
  const float* init_vecs = (const float*)d_in[0];
  const float* W1  = (const float*)d_in[1];
  const float* b1  = (const float*)d_in[2];
  const float* W2  = (const float*)d_in[3];
  const float* b2  = (const float*)d_in[4];
  const float* eW1 = (const float*)d_in[5];
  const float* eb1 = (const float*)d_in[6];
  const float* eW2 = (const float*)d_in[7];
  const float* eb2 = (const float*)d_in[8];
  const float* pos = (const float*)d_in[9];
  const float* neg = (const float*)d_in[10];
  const float* tgt = (const float*)d_in[11];
  const int* pars  = (const int*)d_in[13];
  const int* rules = (const int*)d_in[14];
  const int* mask  = (const int*)d_in[15];

  char* ws = (char*)d_ws;
  unsigned short* vech = (unsigned short*)(ws + OFF_VECH);
  unsigned short* vecl = (unsigned short*)(ws + OFF_VECL);
  float*    val   = (float*)(ws + OFF_VAL);
  unsigned* done  = (unsigned*)(ws + OFF_CNT);
  double*   acc   = (double*)(ws + OFF_ACC);
  int*      kcnt  = (int*)(ws + OFF_KCNT);
  int*      kofs  = (int*)(ws + OFF_KOFS);
  int*      nlp   = (int*)(ws + OFF_NL);
  int*      tpl   = (int*)(ws + OFF_TPL);
  int*      brows = (int*)(ws + OFF_BROWS);
  short*    Ws    = (short*)(ws + OFF_WSPLIT);

  zero_scratch<<<1, 256, 0, stream>>>(done, acc);
  prepass<<<1, 1024, 0, stream>>>(pars, rules, kcnt, kofs, brows, tpl, nlp);
  init_convert<<<128, 256, 0, stream>>>(init_vecs, vech, vecl);
  presplit<<<192, 512, 0, stream>>>(W1, W2, Ws);
  scan_kernel<<<256, BTH, 0, stream>>>(Ws, b1, b2, pars, vech, vecl,
                                       kcnt, kofs, brows, tpl, nlp, done);
  reduce_pn<<<128, 256, 0, stream>>>(pos, neg, acc);
  eval_kernel<<<1024, 256, 0, stream>>>(vech, vecl, mask, eW1, eb1, eW2, eb2, val);
  loss_kernel<<<128, 256, 0, stream>>>(val, pos, neg, tgt, acc);
  writeout<<<1, 1, 0, stream>>>(acc, (float*)d_out);
}